// Round 1
// baseline (588.263 us; speedup 1.0000x reference)
//
#include <hip/hip_runtime.h>
#include <hip/hip_bf16.h>
#include <math.h>

using f32x4  = __attribute__((ext_vector_type(4))) float;
using bf16x8 = __attribute__((ext_vector_type(8))) short;
using s16x4  = __attribute__((ext_vector_type(4))) short;

#define TT 128
#define BB 256
#define II 512
#define HH 1024
#define BM 128
#define BH 64
#define BK 64
#define NTHREADS 256

__device__ __forceinline__ short f2bf(float f) {
    unsigned u = __float_as_uint(f);
    u = u + 0x7FFFu + ((u >> 16) & 1u);   // round-nearest-even
    return (short)(u >> 16);
}

__device__ __forceinline__ float sigmoid_f(float x) {
    float e = __expf(-fabsf(x));
    float s = 1.0f / (1.0f + e);
    return x >= 0.0f ? s : 1.0f - s;
}

__device__ __forceinline__ float tanh_f(float x) {
    float e = __expf(-2.0f * fabsf(x));
    float t = (1.0f - e) / (1.0f + e);
    return x >= 0.0f ? t : -t;
}

// out[b,t,h] = (1-z)*n ; z = sigmoid(gi_z + bhh_z) ; r = sigmoid(gi_r + bhh_r)
// n = tanh(gi_n + r*bhh_n) ; gi = A @ Wih^T + bih ; A = input_seq (T*B, I)
__global__ __launch_bounds__(NTHREADS, 2)
void gru_fused_kernel(const float* __restrict__ A,     // (T*B, I)
                      const float* __restrict__ Wih,   // (3H, I)
                      const float* __restrict__ bih,   // (3H)
                      const float* __restrict__ bhh,   // (3H)
                      float* __restrict__ out)         // (B, T, H)
{
    __shared__ short As[BM * BK];        // bf16 bits, XOR-swizzled rows
    __shared__ short Ws[3 * BH * BK];    // 192 x 64

    const int tid  = threadIdx.x;
    const int wid  = tid >> 6;
    const int lane = tid & 63;
    const int l15  = lane & 15;
    const int l4   = lane >> 4;

    const int mtile = blockIdx.x >> 4;   // 256 m-tiles
    const int htile = blockIdx.x & 15;   // 16 h-tiles (consecutive blocks share A tile -> L2)
    const int m0 = mtile * BM;
    const int h0 = htile * BH;

    // staging decomposition: thread covers rows (i*16 + rbase), float4-col c4
    const int rbase = tid >> 4;          // 0..15
    const int c4    = tid & 15;          // 0..15
    const int swz   = (rbase & 7) << 3;  // XOR in short units (==16B in bytes)

    f32x4 acc[2][12];
    #pragma unroll
    for (int i = 0; i < 2; ++i)
        #pragma unroll
        for (int j = 0; j < 12; ++j)
            acc[i][j] = (f32x4){0.f, 0.f, 0.f, 0.f};

    for (int kt = 0; kt < II / BK; ++kt) {
        const int k0 = kt * BK;
        __syncthreads();   // previous tile's MFMA reads complete

        // ---- stage A: 128x64 f32 -> bf16 LDS (8 float4 per thread) ----
        const float* Ab = A + (size_t)(m0 + rbase) * II + k0 + c4 * 4;
        #pragma unroll
        for (int i = 0; i < 8; ++i) {
            f32x4 v = *(const f32x4*)(Ab + (size_t)i * 16 * II);
            s16x4 hv;
            hv.x = f2bf(v.x); hv.y = f2bf(v.y); hv.z = f2bf(v.z); hv.w = f2bf(v.w);
            const int idx = (i * 16 + rbase) * BK + ((c4 * 4) ^ swz);
            *(s16x4*)(As + idx) = hv;
        }
        // ---- stage W: 192x64 f32 -> bf16 LDS (12 float4 per thread) ----
        #pragma unroll
        for (int i = 0; i < 12; ++i) {
            const int row = i * 16 + rbase;     // 0..191 = gate*64 + r
            const int g   = row >> 6;
            const int r   = row & 63;
            f32x4 v = *(const f32x4*)(Wih + (size_t)(g * HH + h0 + r) * II + k0 + c4 * 4);
            s16x4 hv;
            hv.x = f2bf(v.x); hv.y = f2bf(v.y); hv.z = f2bf(v.z); hv.w = f2bf(v.w);
            const int idx = row * BK + ((c4 * 4) ^ swz);
            *(s16x4*)(Ws + idx) = hv;
        }
        __syncthreads();   // staging visible

        // ---- MFMA: wave owns rows [wid*32, wid*32+32), all 192 gate cols ----
        #pragma unroll
        for (int kk = 0; kk < 2; ++kk) {
            const int kc = kk * 32 + l4 * 8;
            const int r0 = wid * 32 + l15;
            const int r1 = r0 + 16;
            bf16x8 a0 = *(const bf16x8*)(As + r0 * BK + (kc ^ ((r0 & 7) << 3)));
            bf16x8 a1 = *(const bf16x8*)(As + r1 * BK + (kc ^ ((r1 & 7) << 3)));
            #pragma unroll
            for (int nf = 0; nf < 12; ++nf) {
                const int rn = nf * 16 + l15;
                bf16x8 b = *(const bf16x8*)(Ws + rn * BK + (kc ^ ((rn & 7) << 3)));
                acc[0][nf] = __builtin_amdgcn_mfma_f32_16x16x32_bf16(a0, b, acc[0][nf], 0, 0, 0);
                acc[1][nf] = __builtin_amdgcn_mfma_f32_16x16x32_bf16(a1, b, acc[1][nf], 0, 0, 0);
            }
        }
    }

    // ---- fused GRU epilogue + transposed store ----
    // frag nf: gate r; nf+4: gate z; nf+8: gate n -- same lane/reg = same (row,col)
    #pragma unroll
    for (int nf = 0; nf < 4; ++nf) {
        const int h = h0 + nf * 16 + l15;
        const float bir = bih[h]          + bhh[h];
        const float biz = bih[HH + h]     + bhh[HH + h];
        const float bin = bih[2 * HH + h];
        const float bhn = bhh[2 * HH + h];
        #pragma unroll
        for (int mf = 0; mf < 2; ++mf) {
            const f32x4 ra = acc[mf][nf];
            const f32x4 za = acc[mf][nf + 4];
            const f32x4 na = acc[mf][nf + 8];
            #pragma unroll
            for (int j = 0; j < 4; ++j) {
                const int m = m0 + wid * 32 + mf * 16 + l4 * 4 + j;
                const int t = m >> 8;          // B = 256
                const int b = m & 255;
                const float r = sigmoid_f(ra[j] + bir);
                const float z = sigmoid_f(za[j] + biz);
                const float n = tanh_f(na[j] + bin + r * bhn);
                out[(size_t)b * (TT * HH) + (size_t)t * HH + h] = (1.0f - z) * n;
            }
        }
    }
}

extern "C" void kernel_launch(void* const* d_in, const int* in_sizes, int n_in,
                              void* d_out, int out_size, void* d_ws, size_t ws_size,
                              hipStream_t stream) {
    const float* input = (const float*)d_in[0];   // (T,B,I)
    const float* Wih   = (const float*)d_in[1];   // (3H,I)
    // d_in[2] = W_hh: unused (h0 == 0)
    const float* bih   = (const float*)d_in[3];
    const float* bhh   = (const float*)d_in[4];
    float* out = (float*)d_out;

    const int nblocks = (TT * BB / BM) * (HH / BH);   // 256 * 16 = 4096
    gru_fused_kernel<<<dim3(nblocks), dim3(NTHREADS), 0, stream>>>(input, Wih, bih, bhh, out);
}

// Round 2
// 318.626 us; speedup vs baseline: 1.8462x; 1.8462x over previous
//
#include <hip/hip_runtime.h>
#include <hip/hip_bf16.h>

using f32x4  = __attribute__((ext_vector_type(4))) float;
using bf16x8 = __attribute__((ext_vector_type(8))) short;
using s16x4  = __attribute__((ext_vector_type(4))) short;

#define TT 128
#define BB 256
#define II 512
#define HH 1024
#define MM (TT * BB)
#define BM 128
#define BH 64
#define BK 64
#define NTHREADS 256

__device__ __forceinline__ short f2bf(float f) {
    unsigned u = __float_as_uint(f);
    u = u + 0x7FFFu + ((u >> 16) & 1u);   // round-nearest-even
    return (short)(u >> 16);
}

__device__ __forceinline__ float sigmoid_f(float x) {
    float e = __expf(-fabsf(x));
    float s = 1.0f / (1.0f + e);
    return x >= 0.0f ? s : 1.0f - s;
}

__device__ __forceinline__ float tanh_f(float x) {
    float e = __expf(-2.0f * fabsf(x));
    float t = (1.0f - e) / (1.0f + e);
    return x >= 0.0f ? t : -t;
}

__device__ __forceinline__ void gload_lds16(const void* g, void* l) {
    __builtin_amdgcn_global_load_lds((const __attribute__((address_space(1))) unsigned*)g,
                                     (__attribute__((address_space(3))) unsigned*)l,
                                     16, 0, 0);
}

// ---- f32 -> bf16 bulk convert (memory-bound) ----
__global__ __launch_bounds__(256)
void cvt_bf16_kernel(const float* __restrict__ src, short* __restrict__ dst, int n8) {
    const int stride = gridDim.x * blockDim.x;
    for (int i = blockIdx.x * blockDim.x + threadIdx.x; i < n8; i += stride) {
        f32x4 v0 = ((const f32x4*)src)[2 * i];
        f32x4 v1 = ((const f32x4*)src)[2 * i + 1];
        bf16x8 o;
        o[0] = f2bf(v0.x); o[1] = f2bf(v0.y); o[2] = f2bf(v0.z); o[3] = f2bf(v0.w);
        o[4] = f2bf(v1.x); o[5] = f2bf(v1.y); o[6] = f2bf(v1.z); o[7] = f2bf(v1.w);
        ((bf16x8*)dst)[i] = o;
    }
}

// ---- fused GEMM + GRU epilogue, bf16 inputs, global_load_lds staging ----
// out[b,t,h] = (1-z)*n ; z = sigmoid(gi_z + bhh_z) ; r = sigmoid(gi_r + bhh_r)
// n = tanh(gi_n + r*bhh_n) ; gi = A @ Wih^T + bih
__global__ __launch_bounds__(NTHREADS, 3)
void gru_gemm_kernel(const short* __restrict__ Abf,   // (M, I) bf16
                     const short* __restrict__ Wbf,   // (3H, I) bf16
                     const float* __restrict__ bih,
                     const float* __restrict__ bhh,
                     float* __restrict__ out)         // (B, T, H) f32
{
    __shared__ short As[BM * BK];       // 16 KB, XOR-swizzled image
    __shared__ short Ws[3 * BH * BK];   // 24 KB

    const int tid  = threadIdx.x;
    const int wid  = tid >> 6;
    const int lane = tid & 63;
    const int l15  = lane & 15;
    const int l4   = lane >> 4;

    const int mtile = blockIdx.x >> 4;   // 256 m-tiles
    const int htile = blockIdx.x & 15;   // 16 h-tiles; consecutive blocks share A tile
    const int m0 = mtile * BM;
    const int h0 = htile * BH;

    // staging: one global_load_lds covers 8 rows x 128B; lane -> (sub-row, 16B chunk)
    const int lr8 = lane >> 3;                 // 0..7 sub-row
    const int lc  = lane & 7;                  // 0..7 chunk
    const int csw = (lc * 16) ^ (lr8 << 4);    // pre-swizzled byte col within 128B slab

    f32x4 acc[2][12];
    #pragma unroll
    for (int i = 0; i < 2; ++i)
        #pragma unroll
        for (int j = 0; j < 12; ++j)
            acc[i][j] = (f32x4){0.f, 0.f, 0.f, 0.f};

    const char* Ab = (const char*)Abf;
    const char* Wb = (const char*)Wbf;

    for (int kt = 0; kt < II / BK; ++kt) {
        const int kb = kt * (BK * 2);   // byte offset of K-slab within a row (row = 1024 B)

        // ---- stage A: 16 x 1KB instructions, 4 per wave ----
        #pragma unroll
        for (int j = 0; j < 4; ++j) {
            const int it  = wid * 4 + j;
            const int row = it * 8 + lr8;          // 0..127
            gload_lds16(Ab + (size_t)(m0 + row) * (II * 2) + kb + csw,
                        (char*)As + it * 1024);
        }
        // ---- stage W: 24 x 1KB instructions, 6 per wave ----
        #pragma unroll
        for (int j = 0; j < 6; ++j) {
            const int iw  = wid * 6 + j;
            const int row = iw * 8 + lr8;          // 0..191 = gate*64 + r
            const int g   = row >> 6;
            const int wr  = row & 63;
            gload_lds16(Wb + (size_t)(g * HH + h0 + wr) * (II * 2) + kb + csw,
                        (char*)Ws + iw * 1024);
        }
        __syncthreads();   // vmcnt(0) drain: staging visible

        // ---- MFMA: wave owns M-rows [wid*32, wid*32+32), all 192 gate cols ----
        const int xsw = (l15 & 7) << 4;
        #pragma unroll
        for (int kk = 0; kk < 2; ++kk) {
            const int cb = kk * 64 + l4 * 16;      // byte col of 8-elem K fragment
            const int r0 = wid * 32 + l15;
            bf16x8 a0 = *(const bf16x8*)((const char*)As + r0 * 128 + (cb ^ xsw));
            bf16x8 a1 = *(const bf16x8*)((const char*)As + (r0 + 16) * 128 + (cb ^ xsw));
            #pragma unroll
            for (int nf = 0; nf < 12; ++nf) {
                const int rn = nf * 16 + l15;
                bf16x8 b = *(const bf16x8*)((const char*)Ws + rn * 128 + (cb ^ xsw));
                acc[0][nf] = __builtin_amdgcn_mfma_f32_16x16x32_bf16(a0, b, acc[0][nf], 0, 0, 0);
                acc[1][nf] = __builtin_amdgcn_mfma_f32_16x16x32_bf16(a1, b, acc[1][nf], 0, 0, 0);
            }
        }
        __syncthreads();   // compute done before next-tile overwrite
    }

    // ---- fused GRU epilogue + transposed store ----
    // frag nf: gate r; nf+4: gate z; nf+8: gate n -- same lane/reg = same (row,col)
    #pragma unroll
    for (int nf = 0; nf < 4; ++nf) {
        const int h = h0 + nf * 16 + l15;
        const float bir = bih[h]          + bhh[h];
        const float biz = bih[HH + h]     + bhh[HH + h];
        const float bin = bih[2 * HH + h];
        const float bhn = bhh[2 * HH + h];
        #pragma unroll
        for (int mf = 0; mf < 2; ++mf) {
            const f32x4 ra = acc[mf][nf];
            const f32x4 za = acc[mf][nf + 4];
            const f32x4 na = acc[mf][nf + 8];
            #pragma unroll
            for (int j = 0; j < 4; ++j) {
                const int m = m0 + wid * 32 + mf * 16 + l4 * 4 + j;
                const int t = m >> 8;          // B = 256
                const int b = m & 255;
                const float r = sigmoid_f(ra[j] + bir);
                const float z = sigmoid_f(za[j] + biz);
                const float n = tanh_f(na[j] + bin + r * bhn);
                out[(size_t)b * (TT * HH) + (size_t)t * HH + h] = (1.0f - z) * n;
            }
        }
    }
}

// ---- round-0 fallback (f32 loads + in-kernel conversion), used if ws too small ----
__global__ __launch_bounds__(NTHREADS, 2)
void gru_fused_kernel(const float* __restrict__ A,
                      const float* __restrict__ Wih,
                      const float* __restrict__ bih,
                      const float* __restrict__ bhh,
                      float* __restrict__ out)
{
    __shared__ short As[BM * BK];
    __shared__ short Ws[3 * BH * BK];

    const int tid  = threadIdx.x;
    const int wid  = tid >> 6;
    const int lane = tid & 63;
    const int l15  = lane & 15;
    const int l4   = lane >> 4;

    const int mtile = blockIdx.x >> 4;
    const int htile = blockIdx.x & 15;
    const int m0 = mtile * BM;
    const int h0 = htile * BH;

    const int rbase = tid >> 4;
    const int c4    = tid & 15;
    const int swz   = (rbase & 7) << 3;

    f32x4 acc[2][12];
    #pragma unroll
    for (int i = 0; i < 2; ++i)
        #pragma unroll
        for (int j = 0; j < 12; ++j)
            acc[i][j] = (f32x4){0.f, 0.f, 0.f, 0.f};

    for (int kt = 0; kt < II / BK; ++kt) {
        const int k0 = kt * BK;
        __syncthreads();
        const float* Ab = A + (size_t)(m0 + rbase) * II + k0 + c4 * 4;
        #pragma unroll
        for (int i = 0; i < 8; ++i) {
            f32x4 v = *(const f32x4*)(Ab + (size_t)i * 16 * II);
            s16x4 hv;
            hv.x = f2bf(v.x); hv.y = f2bf(v.y); hv.z = f2bf(v.z); hv.w = f2bf(v.w);
            const int idx = (i * 16 + rbase) * BK + ((c4 * 4) ^ swz);
            *(s16x4*)(As + idx) = hv;
        }
        #pragma unroll
        for (int i = 0; i < 12; ++i) {
            const int row = i * 16 + rbase;
            const int g   = row >> 6;
            const int r   = row & 63;
            f32x4 v = *(const f32x4*)(Wih + (size_t)(g * HH + h0 + r) * II + k0 + c4 * 4);
            s16x4 hv;
            hv.x = f2bf(v.x); hv.y = f2bf(v.y); hv.z = f2bf(v.z); hv.w = f2bf(v.w);
            const int idx = row * BK + ((c4 * 4) ^ swz);
            *(s16x4*)(Ws + idx) = hv;
        }
        __syncthreads();

        #pragma unroll
        for (int kk = 0; kk < 2; ++kk) {
            const int kc = kk * 32 + l4 * 8;
            const int r0 = wid * 32 + l15;
            const int r1 = r0 + 16;
            bf16x8 a0 = *(const bf16x8*)(As + r0 * BK + (kc ^ ((r0 & 7) << 3)));
            bf16x8 a1 = *(const bf16x8*)(As + r1 * BK + (kc ^ ((r1 & 7) << 3)));
            #pragma unroll
            for (int nf = 0; nf < 12; ++nf) {
                const int rn = nf * 16 + l15;
                bf16x8 b = *(const bf16x8*)(Ws + rn * BK + (kc ^ ((rn & 7) << 3)));
                acc[0][nf] = __builtin_amdgcn_mfma_f32_16x16x32_bf16(a0, b, acc[0][nf], 0, 0, 0);
                acc[1][nf] = __builtin_amdgcn_mfma_f32_16x16x32_bf16(a1, b, acc[1][nf], 0, 0, 0);
            }
        }
    }

    #pragma unroll
    for (int nf = 0; nf < 4; ++nf) {
        const int h = h0 + nf * 16 + l15;
        const float bir = bih[h]          + bhh[h];
        const float biz = bih[HH + h]     + bhh[HH + h];
        const float bin = bih[2 * HH + h];
        const float bhn = bhh[2 * HH + h];
        #pragma unroll
        for (int mf = 0; mf < 2; ++mf) {
            const f32x4 ra = acc[mf][nf];
            const f32x4 za = acc[mf][nf + 4];
            const f32x4 na = acc[mf][nf + 8];
            #pragma unroll
            for (int j = 0; j < 4; ++j) {
                const int m = m0 + wid * 32 + mf * 16 + l4 * 4 + j;
                const int t = m >> 8;
                const int b = m & 255;
                const float r = sigmoid_f(ra[j] + bir);
                const float z = sigmoid_f(za[j] + biz);
                const float n = tanh_f(na[j] + bin + r * bhn);
                out[(size_t)b * (TT * HH) + (size_t)t * HH + h] = (1.0f - z) * n;
            }
        }
    }
}

extern "C" void kernel_launch(void* const* d_in, const int* in_sizes, int n_in,
                              void* d_out, int out_size, void* d_ws, size_t ws_size,
                              hipStream_t stream) {
    const float* input = (const float*)d_in[0];   // (T,B,I)
    const float* Wih   = (const float*)d_in[1];   // (3H,I)
    // d_in[2] = W_hh: unused (h0 == 0)
    const float* bih   = (const float*)d_in[3];
    const float* bhh   = (const float*)d_in[4];
    float* out = (float*)d_out;

    const size_t nA = (size_t)MM * II;          // 16.78M elems
    const size_t nW = (size_t)3 * HH * II;      // 1.57M elems
    const size_t need = (nA + nW) * sizeof(short);

    const int nblocks = (MM / BM) * (HH / BH);  // 4096

    if (ws_size >= need) {
        short* Abf = (short*)d_ws;
        short* Wbf = Abf + nA;
        cvt_bf16_kernel<<<2048, 256, 0, stream>>>(input, Abf, (int)(nA / 8));
        cvt_bf16_kernel<<<768,  256, 0, stream>>>(Wih,   Wbf, (int)(nW / 8));
        gru_gemm_kernel<<<nblocks, NTHREADS, 0, stream>>>(Abf, Wbf, bih, bhh, out);
    } else {
        gru_fused_kernel<<<nblocks, NTHREADS, 0, stream>>>(input, Wih, bih, bhh, out);
    }
}